// Round 9
// baseline (97.826 us; speedup 1.0000x reference)
//
#include <hip/hip_runtime.h>

#define L2E 1.44269504088896340736f

typedef __attribute__((ext_vector_type(8))) short bf16x8;
typedef __attribute__((ext_vector_type(4))) float f32x4;

__device__ __forceinline__ unsigned bf16_rne(float v) {
    unsigned x = __float_as_uint(v);
    return (x + 0x7FFFu + ((x >> 16) & 1u)) >> 16;
}

__device__ __forceinline__ void cvt_hilo4(float4 v, uint2* hi, uint2* lo) {
    unsigned h0 = bf16_rne(v.x), h1 = bf16_rne(v.y), h2 = bf16_rne(v.z), h3 = bf16_rne(v.w);
    float f0 = __uint_as_float(h0 << 16), f1 = __uint_as_float(h1 << 16);
    float f2 = __uint_as_float(h2 << 16), f3 = __uint_as_float(h3 << 16);
    unsigned l0 = bf16_rne(v.x - f0), l1 = bf16_rne(v.y - f1);
    unsigned l2 = bf16_rne(v.z - f2), l3 = bf16_rne(v.w - f3);
    hi->x = h0 | (h1 << 16); hi->y = h2 | (h3 << 16);
    lo->x = l0 | (l1 << 16); lo->y = l2 | (l3 << 16);
}

// Single cooperative launch, per-batch flag sync (NO cg::grid sync).
// b = bid & 15 (same-batch blocks share an XCD under round-robin dispatch),
// itile = bid >> 4. itile==0 blocks produce h/e for their batch via
// x @ [W ; Acat*W]^T (e computed straight from x — no h->e chain), then
// release flag[b]; all blocks acquire-poll flag[b] and run softmax+PV.
__global__ __launch_bounds__(512) void fused_gat(
    const float* __restrict__ x, const int* __restrict__ adj,
    const int* __restrict__ adjin, const int* __restrict__ adjout,
    const float* __restrict__ W, const float* __restrict__ A,
    const float* __restrict__ ab,
    unsigned short* __restrict__ hTg, float* __restrict__ edTg,
    float* __restrict__ esg, int* __restrict__ flags,
    float* __restrict__ out)
{
    __shared__ unsigned short bmh[96 * 136], bml[96 * 136];  // B = [W ; C] hi/lo
    __shared__ unsigned short xh[32 * 136], xl[32 * 136];    // x chunk hi/lo
    __shared__ __align__(16) char uni[46080];                // setup / phase-2 union
    unsigned short* wth = (unsigned short*)uni;              // 128x72 u16 = 18432
    unsigned short* wtl = (unsigned short*)(uni + 18432);
    unsigned short* ach = (unsigned short*)(uni + 36864);    // 32x72 u16 = 4608
    unsigned short* acl = (unsigned short*)(uni + 41472);
    unsigned short* Ph  = (unsigned short*)uni;              // 16x264 u16 = 8448
    float*          red = (float*)(uni + 8448);              // 4x272 f32 = 4352

    const int t = threadIdx.x;
    const int bid = blockIdx.x;
    const int b = bid & 15;
    const int itile = bid >> 4;
    const int i0 = itile * 16;
    const int lane = t & 63, wv = t >> 6;
    const int g = lane >> 5, q = lane & 31;
    const int rloc = wv * 2 + g;                 // 0..15 own-row
    const long gi = (long)(b * 256 + i0 + rloc);
    const int ml = lane & 15, kb = lane >> 4;

    if (itile == 0) {
        // =================== PRODUCER (one block per batch) ===================
        const float4* xb4 = (const float4*)(x + (size_t)b * 256 * 128);
        float4 xv0 = xb4[t], xv1 = xb4[t + 512];          // chunk-0 prefetch
        const float abv_ = (ml < 12) ? ab[ml] : 0.f;

        // stage W (rows 0..63 of BM) + transposed Wt for the C-GEMM
#pragma unroll
        for (int pp = 0; pp < 4; ++pp) {
            int q4 = t + 512 * pp;                        // 0..2047
            int r = q4 >> 5, c4 = (q4 & 31) * 4;
            float4 v = *(const float4*)&W[4 * q4];
            uint2 hi, lo; cvt_hilo4(v, &hi, &lo);
            *(uint2*)&bmh[r * 136 + c4] = hi;
            *(uint2*)&bml[r * 136 + c4] = lo;
            wth[(c4 + 0) * 72 + r] = (unsigned short)hi.x;
            wth[(c4 + 1) * 72 + r] = (unsigned short)(hi.x >> 16);
            wth[(c4 + 2) * 72 + r] = (unsigned short)hi.y;
            wth[(c4 + 3) * 72 + r] = (unsigned short)(hi.y >> 16);
            wtl[(c4 + 0) * 72 + r] = (unsigned short)lo.x;
            wtl[(c4 + 1) * 72 + r] = (unsigned short)(lo.x >> 16);
            wtl[(c4 + 2) * 72 + r] = (unsigned short)lo.y;
            wtl[(c4 + 3) * 72 + r] = (unsigned short)(lo.y >> 16);
        }
        {   // stage Acat = [A1;A2] (24x64 pad 32)
            int n = t >> 4, d4 = (t & 15) * 4;
            float4 v = make_float4(0.f, 0.f, 0.f, 0.f);
            if (n < 24) {
                int nn = (n < 12) ? n : n - 12;
                v = *(const float4*)&A[nn * 128 + ((n < 12) ? 0 : 64) + d4];
            }
            uint2 hi, lo; cvt_hilo4(v, &hi, &lo);
            *(uint2*)&ach[n * 72 + d4] = hi;
            *(uint2*)&acl[n * 72 + d4] = lo;
        }
        __syncthreads();

        // C = Acat @ W  (24x128, into BM rows 64..87) — M2 x N8 tiles, K=64
        {
            const int cmt = wv & 1, cnt0 = wv >> 1;
#pragma unroll
            for (int tt = 0; tt < 2; ++tt) {
                const int nt = cnt0 + tt * 4;
                f32x4 cacc = {0.f, 0.f, 0.f, 0.f};
#pragma unroll
                for (int ks = 0; ks < 2; ++ks) {
                    int ko = ks * 32 + kb * 8;
                    bf16x8 ah = *(const bf16x8*)&ach[(cmt * 16 + ml) * 72 + ko];
                    bf16x8 al = *(const bf16x8*)&acl[(cmt * 16 + ml) * 72 + ko];
                    bf16x8 bh = *(const bf16x8*)&wth[(nt * 16 + ml) * 72 + ko];
                    bf16x8 bl = *(const bf16x8*)&wtl[(nt * 16 + ml) * 72 + ko];
                    cacc = __builtin_amdgcn_mfma_f32_16x16x32_bf16(ah, bh, cacc, 0, 0, 0);
                    cacc = __builtin_amdgcn_mfma_f32_16x16x32_bf16(ah, bl, cacc, 0, 0, 0);
                    cacc = __builtin_amdgcn_mfma_f32_16x16x32_bf16(al, bh, cacc, 0, 0, 0);
                }
#pragma unroll
                for (int r = 0; r < 4; ++r) {
                    int m = cmt * 16 + kb * 4 + r;
                    int n = nt * 16 + ml;
                    if (m < 24) {
                        unsigned hi = bf16_rne(cacc[r]);
                        bmh[(64 + m) * 136 + n] = (unsigned short)hi;
                        bml[(64 + m) * 136 + n] =
                            (unsigned short)bf16_rne(cacc[r] - __uint_as_float(hi << 16));
                    }
                }
            }
        }
        __syncthreads();

        // main GEMM: 8 chunks x 32 rows: [h | e] = x_chunk @ BM^T
        const int mt = wv >> 2;          // M half
        const int ntA = wv & 3;          // W tile (h output)
        const bool two = (ntA < 2);
        const int ntB = ntA + 4;         // C tile (e output) for waves 0,1,4,5
        for (int c = 0; c < 8; ++c) {
            {   // staged x regs -> LDS
                int r0 = t >> 5, c4 = (t & 31) * 4;
                uint2 hi, lo; cvt_hilo4(xv0, &hi, &lo);
                *(uint2*)&xh[r0 * 136 + c4] = hi;
                *(uint2*)&xl[r0 * 136 + c4] = lo;
                int r1 = (t + 512) >> 5;
                cvt_hilo4(xv1, &hi, &lo);
                *(uint2*)&xh[r1 * 136 + c4] = hi;
                *(uint2*)&xl[r1 * 136 + c4] = lo;
            }
            __syncthreads();

            f32x4 acc1 = {0.f, 0.f, 0.f, 0.f}, acc2 = {0.f, 0.f, 0.f, 0.f};
#pragma unroll
            for (int ks = 0; ks < 4; ++ks) {
                int ko = ks * 32 + kb * 8;
                bf16x8 axh = *(const bf16x8*)&xh[(mt * 16 + ml) * 136 + ko];
                bf16x8 axl = *(const bf16x8*)&xl[(mt * 16 + ml) * 136 + ko];
                bf16x8 b1h = *(const bf16x8*)&bmh[(ntA * 16 + ml) * 136 + ko];
                bf16x8 b1l = *(const bf16x8*)&bml[(ntA * 16 + ml) * 136 + ko];
                acc1 = __builtin_amdgcn_mfma_f32_16x16x32_bf16(axh, b1h, acc1, 0, 0, 0);
                acc1 = __builtin_amdgcn_mfma_f32_16x16x32_bf16(axh, b1l, acc1, 0, 0, 0);
                acc1 = __builtin_amdgcn_mfma_f32_16x16x32_bf16(axl, b1h, acc1, 0, 0, 0);
                if (two) {
                    bf16x8 b2h = *(const bf16x8*)&bmh[(ntB * 16 + ml) * 136 + ko];
                    bf16x8 b2l = *(const bf16x8*)&bml[(ntB * 16 + ml) * 136 + ko];
                    acc2 = __builtin_amdgcn_mfma_f32_16x16x32_bf16(axh, b2h, acc2, 0, 0, 0);
                    acc2 = __builtin_amdgcn_mfma_f32_16x16x32_bf16(axh, b2l, acc2, 0, 0, 0);
                    acc2 = __builtin_amdgcn_mfma_f32_16x16x32_bf16(axl, b2h, acc2, 0, 0, 0);
                }
            }
            const int jb = c * 32 + mt * 16 + kb * 4;
            {   // h -> hTg packed u32 (2 bf16 along j)
                const int d = ntA * 16 + ml;
                unsigned w0 = bf16_rne(acc1[0]) | (bf16_rne(acc1[1]) << 16);
                unsigned w1 = bf16_rne(acc1[2]) | (bf16_rne(acc1[3]) << 16);
                *(unsigned*)&hTg[(size_t)(b * 64 + d) * 256 + jb] = w0;
                *(unsigned*)&hTg[(size_t)(b * 64 + d) * 256 + jb + 2] = w1;
            }
            if (two) {
                const int ec = (ntB - 4) * 16 + ml;
                if (ec < 12) {
#pragma unroll
                    for (int r = 0; r < 4; ++r)
                        esg[(size_t)(b * 256 + jb + r) * 12 + ec] = (acc2[r] + abv_) * L2E;
                } else if (ec < 24) {
                    float4 ev;
                    ev.x = acc2[0] * L2E; ev.y = acc2[1] * L2E;
                    ev.z = acc2[2] * L2E; ev.w = acc2[3] * L2E;
                    *(float4*)&edTg[(size_t)(b * 12 + ec - 12) * 256 + jb] = ev;
                }
            }
            if (c < 7) {
                const float4* nb = (const float4*)(x + ((size_t)b * 256 + (c + 1) * 32) * 128);
                xv0 = nb[t]; xv1 = nb[t + 512];
            }
            __syncthreads();
        }
        __threadfence();                  // drain + make stores device-visible
        __syncthreads();
        if (t == 0)
            __hip_atomic_store(&flags[b * 16], 1, __ATOMIC_RELEASE, __HIP_MEMORY_SCOPE_AGENT);
    }

    // ---- mask prefetch (issues before/overlaps the poll) ----
    int4 Ma0, Ma1, Mb0, Mb1, Mc0, Mc1;
    {
        const int4* mp0 = (const int4*)(adj    + gi * 256 + 8 * q);
        const int4* mp1 = (const int4*)(adjin  + gi * 256 + 8 * q);
        const int4* mp2 = (const int4*)(adjout + gi * 256 + 8 * q);
        Ma0 = mp0[0]; Ma1 = mp0[1];
        Mb0 = mp1[0]; Mb1 = mp1[1];
        Mc0 = mp2[0]; Mc1 = mp2[1];
    }

    // ---- wait for this batch's producer (acquire invalidates L1) ----
    if (t == 0) {
        while (__hip_atomic_load(&flags[b * 16], __ATOMIC_ACQUIRE, __HIP_MEMORY_SCOPE_AGENT) == 0)
            __builtin_amdgcn_s_sleep(8);
    }
    __syncthreads();

    // =================== PHASE 2: softmax + PV (all blocks) ===================
    float fm[3][8];
    fm[0][0] = (float)Ma0.x; fm[0][1] = (float)Ma0.y; fm[0][2] = (float)Ma0.z; fm[0][3] = (float)Ma0.w;
    fm[0][4] = (float)Ma1.x; fm[0][5] = (float)Ma1.y; fm[0][6] = (float)Ma1.z; fm[0][7] = (float)Ma1.w;
    fm[1][0] = (float)Mb0.x; fm[1][1] = (float)Mb0.y; fm[1][2] = (float)Mb0.z; fm[1][3] = (float)Mb0.w;
    fm[1][4] = (float)Mb1.x; fm[1][5] = (float)Mb1.y; fm[1][6] = (float)Mb1.z; fm[1][7] = (float)Mb1.w;
    fm[2][0] = (float)Mc0.x; fm[2][1] = (float)Mc0.y; fm[2][2] = (float)Mc0.z; fm[2][3] = (float)Mc0.w;
    fm[2][4] = (float)Mc1.x; fm[2][5] = (float)Mc1.y; fm[2][6] = (float)Mc1.z; fm[2][7] = (float)Mc1.w;

    const float4* ep = (const float4*)(esg + gi * 12);
    const float4 eA = ep[0], eB = ep[1], eC = ep[2];
    const float e0[12] = {eA.x, eA.y, eA.z, eA.w, eB.x, eB.y, eB.z, eB.w, eC.x, eC.y, eC.z, eC.w};

    float Pacc[8] = {0.f, 0.f, 0.f, 0.f, 0.f, 0.f, 0.f, 0.f};
#pragma unroll
    for (int hh = 0; hh < 12; ++hh) {
        const int grp = hh >> 2;
        const float4* evp = (const float4*)(edTg + (size_t)(b * 12 + hh) * 256 + 8 * q);
        const float4 ev0 = evp[0], ev1 = evp[1];
        const float evv[8] = {ev0.x, ev0.y, ev0.z, ev0.w, ev1.x, ev1.y, ev1.z, ev1.w};
        float p[8], s = 0.f;
#pragma unroll
        for (int k = 0; k < 8; ++k) {
            float v = e0[hh] + evv[k];
            v = fmaxf(v, 0.01f * v);                     // leaky in log2 domain
            p[k] = __builtin_amdgcn_exp2f(v) * fm[grp][k];
            s += p[k];
        }
#pragma unroll
        for (int off = 16; off >= 1; off >>= 1)
            s += __shfl_xor(s, off);                     // 32-lane group reduce
        const float rinv = __builtin_amdgcn_rcpf(s);
#pragma unroll
        for (int k = 0; k < 8; ++k)
            Pacc[k] += p[k] * rinv;
    }
    {
        uint4 pk;
        pk.x = bf16_rne(Pacc[0]) | (bf16_rne(Pacc[1]) << 16);
        pk.y = bf16_rne(Pacc[2]) | (bf16_rne(Pacc[3]) << 16);
        pk.z = bf16_rne(Pacc[4]) | (bf16_rne(Pacc[5]) << 16);
        pk.w = bf16_rne(Pacc[6]) | (bf16_rne(Pacc[7]) << 16);
        *(uint4*)&Ph[rloc * 264 + 8 * q] = pk;
    }
    __syncthreads();

    // PV: out[16][64] = P[16][256] x hT^T ; K split across wave pairs
    const int nt = wv & 3, kh = wv >> 2;
    const unsigned short* hTb = hTg + (size_t)(b * 64 + nt * 16 + ml) * 256;
    f32x4 acc = {0.f, 0.f, 0.f, 0.f};
#pragma unroll
    for (int ks = 0; ks < 4; ++ks) {
        const int ko = kh * 128 + ks * 32 + kb * 8;
        bf16x8 bh = *(const bf16x8*)&hTb[ko];
        bf16x8 ah = *(const bf16x8*)&Ph[ml * 264 + ko];
        acc = __builtin_amdgcn_mfma_f32_16x16x32_bf16(ah, bh, acc, 0, 0, 0);
    }
    if (kh == 1) {
#pragma unroll
        for (int r = 0; r < 4; ++r)
            red[nt * 272 + (kb * 4 + r) * 17 + ml] = acc[r];
    }
    __syncthreads();
    if (kh == 0) {
#pragma unroll
        for (int r = 0; r < 4; ++r) {
            const int m = kb * 4 + r;        // 0..15
            const float v = (acc[r] + red[nt * 272 + m * 17 + ml]) * (1.0f / 12.0f);
            out[(size_t)(b * 256 + i0 + m) * 64 + nt * 16 + ml] = v;
        }
    }
}

extern "C" void kernel_launch(void* const* d_in, const int* in_sizes, int n_in,
                              void* d_out, int out_size, void* d_ws, size_t ws_size,
                              hipStream_t stream) {
    const float* x    = (const float*)d_in[0];
    const int*   adj  = (const int*)d_in[1];
    const int*   adji = (const int*)d_in[2];
    const int*   adjo = (const int*)d_in[3];
    const float* W    = (const float*)d_in[4];
    const float* A    = (const float*)d_in[5];
    const float* ab   = (const float*)d_in[6];
    float* out = (float*)d_out;

    unsigned short* hTg  = (unsigned short*)d_ws;               // 512 KB
    float* edTg = (float*)((char*)d_ws + (512 << 10));          // 192 KB
    float* esg  = (float*)((char*)d_ws + (704 << 10));          // 192 KB
    int*   flags = (int*)((char*)d_ws + (896 << 10));           // 1 KB (16 x 64 B)

    hipMemsetAsync(flags, 0, 1024, stream);

    void* args[] = {(void*)&x, (void*)&adj, (void*)&adji, (void*)&adjo,
                    (void*)&W, (void*)&A, (void*)&ab,
                    (void*)&hTg, (void*)&edTg, (void*)&esg, (void*)&flags,
                    (void*)&out};
    hipLaunchCooperativeKernel((const void*)fused_gat, dim3(256), dim3(512),
                               args, 0, stream);
}

// Round 10
// 19.128 us; speedup vs baseline: 5.1141x; 5.1141x over previous
//
#include <hip/hip_runtime.h>

#define L2E 1.44269504088896340736f

typedef __attribute__((ext_vector_type(8))) short bf16x8;
typedef __attribute__((ext_vector_type(4))) float f32x4;

__device__ __forceinline__ unsigned bf16_rne(float v) {
    unsigned x = __float_as_uint(v);
    return (x + 0x7FFFu + ((x >> 16) & 1u)) >> 16;
}

__device__ __forceinline__ bf16x8 cvt8(float4 a, float4 b) {
    bf16x8 r;
    r[0] = (short)bf16_rne(a.x); r[1] = (short)bf16_rne(a.y);
    r[2] = (short)bf16_rne(a.z); r[3] = (short)bf16_rne(a.w);
    r[4] = (short)bf16_rne(b.x); r[5] = (short)bf16_rne(b.y);
    r[6] = (short)bf16_rne(b.z); r[7] = (short)bf16_rne(b.w);
    return r;
}

__device__ __forceinline__ bf16x8 cvt8g(const float* p) {
    float4 a = *(const float4*)p;
    float4 b = *(const float4*)(p + 4);
    return cvt8(a, b);
}

// ---- kernel 1 (lean): 512 blocks x 256 thr, 8 rows/block ----------------
// No x/W LDS staging: MFMA fragments built directly from global (L1/L2-hot).
// hi-only bf16 x/W (h err ~3e-3). hT written straight from accumulators.
// Only hsh (2.3 KB LDS) crosses waves for the e-GEMM.
__global__ __launch_bounds__(256) void k1_proj(
    const float* __restrict__ x, const float* __restrict__ W, const float* __restrict__ A,
    const float* __restrict__ ab,
    unsigned short* __restrict__ hTg, float* __restrict__ esg, float* __restrict__ edTg)
{
    __shared__ unsigned short hsh[16 * 72];   // h rows 0..7 valid, bf16

    const int t = threadIdx.x;
    const int b = blockIdx.x >> 5;
    const int ibase = (blockIdx.x & 31) * 8;
    const int row0 = b * 256 + ibase;
    const int lane = t & 63, wv = t >> 6;      // 4 waves
    const int ml = lane & 15, kb = lane >> 4;

    // h-GEMM fragment sources (direct global)
    const int xr = row0 + (ml < 8 ? ml : 0);             // clamp garbage rows in-bounds
    const float* xp = x + (size_t)xr * 128;
    const float* wp = W + (size_t)(wv * 16 + ml) * 128;  // d = wv*16+ml

    // e-phase prefetch (waves 0,1): Acat row n = wv*16+ml, plus bias
    const int n_e = wv * 16 + ml;
    float4 ea0, ea1, ea2, ea3;
    float abv = 0.f;
    if (wv < 2 && n_e < 24) {
        const float* ap = (n_e < 12) ? (A + n_e * 128) : (A + (n_e - 12) * 128 + 64);
        ea0 = *(const float4*)(ap + kb * 8);
        ea1 = *(const float4*)(ap + kb * 8 + 4);
        ea2 = *(const float4*)(ap + 32 + kb * 8);
        ea3 = *(const float4*)(ap + 32 + kb * 8 + 4);
        if (n_e < 12) abv = ab[n_e];
    } else {
        ea0 = ea1 = ea2 = ea3 = make_float4(0.f, 0.f, 0.f, 0.f);
    }

    // h-MFMA: h[8(16)][64] = x @ W^T, K=128, hi-only
    f32x4 acc = {0.f, 0.f, 0.f, 0.f};
#pragma unroll
    for (int ks = 0; ks < 4; ++ks) {
        const int ko = ks * 32 + kb * 8;
        bf16x8 ax = cvt8g(xp + ko);
        bf16x8 bw = cvt8g(wp + ko);
        acc = __builtin_amdgcn_mfma_f32_16x16x32_bf16(ax, bw, acc, 0, 0, 0);
    }

    // store h: only rows m = kb*4+r < 8 are real (8-row block in a 16-row tile)
    if (kb < 2) {
        const int d = wv * 16 + ml;
        // hT direct from acc: packed u32 = 2 bf16 along j
        unsigned w0 = bf16_rne(acc[0]) | (bf16_rne(acc[1]) << 16);
        unsigned w1 = bf16_rne(acc[2]) | (bf16_rne(acc[3]) << 16);
        uint2 pk; pk.x = w0; pk.y = w1;
        *(uint2*)&hTg[(size_t)(b * 64 + d) * 256 + ibase + kb * 4] = pk;
#pragma unroll
        for (int r = 0; r < 4; ++r)
            hsh[(kb * 4 + r) * 72 + d] = (unsigned short)bf16_rne(acc[r]);
    }
    __syncthreads();

    // e-MFMA (waves 0,1): e[8(16)][24(32)] = h[.][64] @ Acat^T, hi-only
    if (wv < 2) {
        bf16x8 eb0 = cvt8(ea0, ea1);
        bf16x8 eb1 = cvt8(ea2, ea3);
        f32x4 e4 = {0.f, 0.f, 0.f, 0.f};
        {
            bf16x8 ah0 = *(const bf16x8*)&hsh[ml * 72 + kb * 8];
            bf16x8 ah1 = *(const bf16x8*)&hsh[ml * 72 + 32 + kb * 8];
            e4 = __builtin_amdgcn_mfma_f32_16x16x32_bf16(ah0, eb0, e4, 0, 0, 0);
            e4 = __builtin_amdgcn_mfma_f32_16x16x32_bf16(ah1, eb1, e4, 0, 0, 0);
        }
        if (kb < 2) {
            if (n_e < 12) {
#pragma unroll
                for (int r = 0; r < 4; ++r)
                    esg[(size_t)(row0 + kb * 4 + r) * 12 + n_e] = (e4[r] + abv) * L2E;
            } else if (n_e < 24) {
                float4 ev;
                ev.x = e4[0] * L2E; ev.y = e4[1] * L2E;
                ev.z = e4[2] * L2E; ev.w = e4[3] * L2E;
                *(float4*)&edTg[(size_t)(b * 12 + (n_e - 12)) * 256 + ibase + kb * 4] = ev;
            }
        }
    }
}

// ---- kernel 2: masked 12-head softmax (no-max, pre-scaled) + MFMA PV ----
// 512 blocks x 256 thr (4 waves); wave = 2 rows (32-lane groups); block = 8 rows.
__global__ __launch_bounds__(256) void k2_attn(
    const int* __restrict__ adj, const int* __restrict__ adjin, const int* __restrict__ adjout,
    const float* __restrict__ esrc, const float* __restrict__ edstT,
    const unsigned short* __restrict__ hTg,
    float* __restrict__ out)
{
    __shared__ unsigned short Ph[16 * 264];   // rows 0..7 = P bf16; rows 8..15 zeroed

    const int t = threadIdx.x;
    const int b  = blockIdx.x >> 5;
    const int i0 = (blockIdx.x & 31) * 8;
    const int lane = t & 63;
    const int wv = t >> 6;                    // 0..3
    const int g = lane >> 5;                  // half-wave -> row parity
    const int q = lane & 31;                  // j-block: j = 8q..8q+7
    const int row = wv * 2 + g;               // 0..7
    const int gi = b * 256 + i0 + row;

    // zero Ph rows 8..15
    {
        uint4* z = (uint4*)&Ph[8 * 264];
        if (t < 264) z[t] = make_uint4(0, 0, 0, 0);
    }

    // masks: 8 j per lane, 2 int4 per type
    const int4* mp0 = (const int4*)(adj    + (size_t)gi * 256 + 8 * q);
    const int4* mp1 = (const int4*)(adjin  + (size_t)gi * 256 + 8 * q);
    const int4* mp2 = (const int4*)(adjout + (size_t)gi * 256 + 8 * q);
    int4 Ma0 = mp0[0], Ma1 = mp0[1];
    int4 Mb0 = mp1[0], Mb1 = mp1[1];
    int4 Mc0 = mp2[0], Mc1 = mp2[1];
    float fm[3][8];
    fm[0][0] = (float)Ma0.x; fm[0][1] = (float)Ma0.y; fm[0][2] = (float)Ma0.z; fm[0][3] = (float)Ma0.w;
    fm[0][4] = (float)Ma1.x; fm[0][5] = (float)Ma1.y; fm[0][6] = (float)Ma1.z; fm[0][7] = (float)Ma1.w;
    fm[1][0] = (float)Mb0.x; fm[1][1] = (float)Mb0.y; fm[1][2] = (float)Mb0.z; fm[1][3] = (float)Mb0.w;
    fm[1][4] = (float)Mb1.x; fm[1][5] = (float)Mb1.y; fm[1][6] = (float)Mb1.z; fm[1][7] = (float)Mb1.w;
    fm[2][0] = (float)Mc0.x; fm[2][1] = (float)Mc0.y; fm[2][2] = (float)Mc0.z; fm[2][3] = (float)Mc0.w;
    fm[2][4] = (float)Mc1.x; fm[2][5] = (float)Mc1.y; fm[2][6] = (float)Mc1.z; fm[2][7] = (float)Mc1.w;

    // e0 (pre-biased, pre-scaled by L2E in k1)
    const float4* ep = (const float4*)(esrc + (size_t)gi * 12);
    const float4 eA = ep[0], eB = ep[1], eC = ep[2];
    const float e0[12] = {eA.x, eA.y, eA.z, eA.w, eB.x, eB.y, eB.z, eB.w, eC.x, eC.y, eC.z, eC.w};

    float Pacc[8] = {0.f, 0.f, 0.f, 0.f, 0.f, 0.f, 0.f, 0.f};
#pragma unroll
    for (int hh = 0; hh < 12; ++hh) {
        const int grp = hh >> 2;
        const float4* evp = (const float4*)(edstT + (size_t)(b * 12 + hh) * 256 + 8 * q);
        const float4 ev0 = evp[0], ev1 = evp[1];
        const float evv[8] = {ev0.x, ev0.y, ev0.z, ev0.w, ev1.x, ev1.y, ev1.z, ev1.w};
        float p[8], s = 0.f;
#pragma unroll
        for (int k = 0; k < 8; ++k) {
            float v = e0[hh] + evv[k];
            v = fmaxf(v, 0.01f * v);                     // leaky in log2 domain
            p[k] = __builtin_amdgcn_exp2f(v) * fm[grp][k];
            s += p[k];
        }
#pragma unroll
        for (int off = 16; off >= 1; off >>= 1)
            s += __shfl_xor(s, off);                     // 32-lane group reduce
        const float rinv = __builtin_amdgcn_rcpf(s);
#pragma unroll
        for (int k = 0; k < 8; ++k)
            Pacc[k] += p[k] * rinv;
    }
    {
        uint4 pk;
        pk.x = bf16_rne(Pacc[0]) | (bf16_rne(Pacc[1]) << 16);
        pk.y = bf16_rne(Pacc[2]) | (bf16_rne(Pacc[3]) << 16);
        pk.z = bf16_rne(Pacc[4]) | (bf16_rne(Pacc[5]) << 16);
        pk.w = bf16_rne(Pacc[6]) | (bf16_rne(Pacc[7]) << 16);
        *(uint4*)&Ph[row * 264 + 8 * q] = pk;
    }
    __syncthreads();

    // PV: out[8][64] = P[8][256] x hT^T ; B-frags from L2; wave -> 16-d slice
    const int ml = lane & 15, kb = lane >> 4;
    const unsigned short* hTb = hTg + ((size_t)b * 64 + wv * 16 + ml) * 256;
    f32x4 acc = {0.f, 0.f, 0.f, 0.f};
#pragma unroll
    for (int ks = 0; ks < 8; ++ks) {
        const int ko = ks * 32 + kb * 8;
        bf16x8 bh = *(const bf16x8*)&hTb[ko];
        bf16x8 ah = *(const bf16x8*)&Ph[ml * 264 + ko];
        acc = __builtin_amdgcn_mfma_f32_16x16x32_bf16(ah, bh, acc, 0, 0, 0);
    }
    if (kb < 2) {
#pragma unroll
        for (int r = 0; r < 4; ++r) {
            const int m = kb * 4 + r;     // 0..7
            out[(size_t)(b * 256 + i0 + m) * 64 + wv * 16 + ml] = acc[r] * (1.0f / 12.0f);
        }
    }
}

extern "C" void kernel_launch(void* const* d_in, const int* in_sizes, int n_in,
                              void* d_out, int out_size, void* d_ws, size_t ws_size,
                              hipStream_t stream) {
    const float* x    = (const float*)d_in[0];
    const int*   adj  = (const int*)d_in[1];
    const int*   adji = (const int*)d_in[2];
    const int*   adjo = (const int*)d_in[3];
    const float* W    = (const float*)d_in[4];
    const float* A    = (const float*)d_in[5];
    const float* ab   = (const float*)d_in[6];
    float* out = (float*)d_out;

    unsigned short* hTg = (unsigned short*)d_ws;              // 512 KB
    float* esg  = (float*)((char*)d_ws + (512 << 10));        // 192 KB
    float* edTg = (float*)((char*)d_ws + (704 << 10));        // 192 KB

    k1_proj<<<512, 256, 0, stream>>>(x, W, A, ab, hTg, esg, edTg);
    k2_attn<<<512, 256, 0, stream>>>(adj, adji, adjo, esg, edTg, hTg, out);
}

// Round 12
// 18.725 us; speedup vs baseline: 5.2244x; 1.0216x over previous
//
#include <hip/hip_runtime.h>

#define L2E 1.44269504088896340736f

typedef __attribute__((ext_vector_type(8))) short bf16x8;
typedef __attribute__((ext_vector_type(4))) float f32x4;

__device__ __forceinline__ unsigned bf16_rne(float v) {
    unsigned x = __float_as_uint(v);
    return (x + 0x7FFFu + ((x >> 16) & 1u)) >> 16;
}

__device__ __forceinline__ void cvt_hilo4(float4 v, uint2* hi, uint2* lo) {
    unsigned h0 = bf16_rne(v.x), h1 = bf16_rne(v.y), h2 = bf16_rne(v.z), h3 = bf16_rne(v.w);
    float f0 = __uint_as_float(h0 << 16), f1 = __uint_as_float(h1 << 16);
    float f2 = __uint_as_float(h2 << 16), f3 = __uint_as_float(h3 << 16);
    unsigned l0 = bf16_rne(v.x - f0), l1 = bf16_rne(v.y - f1);
    unsigned l2 = bf16_rne(v.z - f2), l3 = bf16_rne(v.w - f3);
    hi->x = h0 | (h1 << 16); hi->y = h2 | (h3 << 16);
    lo->x = l0 | (l1 << 16); lo->y = l2 | (l3 << 16);
}

// ---- kernel 1 (R5, all-MFMA, staged): h=x@W^T ; esrc'=(h@A1^T+ab)*L2E ;
// edstT'=(h@A2^T)*L2E ; hT bf16. 256 blocks x 256 thr, 16 rows each.
__global__ __launch_bounds__(256) void k1_proj(
    const float* __restrict__ x, const float* __restrict__ W, const float* __restrict__ A,
    const float* __restrict__ ab,
    unsigned short* __restrict__ hTg, float* __restrict__ esrc, float* __restrict__ edstT)
{
    __shared__ unsigned short xh[16 * 136], xl[16 * 136];
    __shared__ unsigned short wh[64 * 136], wl[64 * 136];
    __shared__ unsigned short Ach[32 * 72], Acl[32 * 72];
    __shared__ unsigned short hsh[16 * 72], hsl[16 * 72];

    const int t = threadIdx.x;
    const int row0 = blockIdx.x * 16;
    const int b = row0 >> 8;
    const int ibase = row0 & 255;

#pragma unroll
    for (int p = 0; p < 2; ++p) {
        int q = t + 256 * p;
        int r = q >> 5, c = (q & 31) * 4;
        float4 v = *(const float4*)&x[row0 * 128 + 4 * q];
        uint2 hi, lo; cvt_hilo4(v, &hi, &lo);
        *(uint2*)&xh[r * 136 + c] = hi;
        *(uint2*)&xl[r * 136 + c] = lo;
    }
#pragma unroll
    for (int p = 0; p < 8; ++p) {
        int q = t + 256 * p;
        int r = q >> 5, c = (q & 31) * 4;
        float4 v = *(const float4*)&W[4 * q];
        uint2 hi, lo; cvt_hilo4(v, &hi, &lo);
        *(uint2*)&wh[r * 136 + c] = hi;
        *(uint2*)&wl[r * 136 + c] = lo;
    }
#pragma unroll
    for (int p = 0; p < 2; ++p) {
        int q = t + 256 * p;
        int n = q >> 4, d = (q & 15) * 4;
        float4 v = make_float4(0.f, 0.f, 0.f, 0.f);
        if (n < 24) {
            int nn = (n < 12) ? n : n - 12;
            v = *(const float4*)&A[nn * 128 + ((n < 12) ? 0 : 64) + d];
        }
        uint2 hi, lo; cvt_hilo4(v, &hi, &lo);
        *(uint2*)&Ach[n * 72 + d] = hi;
        *(uint2*)&Acl[n * 72 + d] = lo;
    }
    __syncthreads();

    const int lane = t & 63;
    const int wv = t >> 6;
    const int ml = lane & 15, kb = lane >> 4;

    f32x4 acc = {0.f, 0.f, 0.f, 0.f};
#pragma unroll
    for (int ks = 0; ks < 4; ++ks) {
        const int ko = ks * 32 + kb * 8;
        bf16x8 axh = *(const bf16x8*)&xh[ml * 136 + ko];
        bf16x8 axl = *(const bf16x8*)&xl[ml * 136 + ko];
        bf16x8 bwh = *(const bf16x8*)&wh[(wv * 16 + ml) * 136 + ko];
        bf16x8 bwl = *(const bf16x8*)&wl[(wv * 16 + ml) * 136 + ko];
        acc = __builtin_amdgcn_mfma_f32_16x16x32_bf16(axh, bwh, acc, 0, 0, 0);
        acc = __builtin_amdgcn_mfma_f32_16x16x32_bf16(axh, bwl, acc, 0, 0, 0);
        acc = __builtin_amdgcn_mfma_f32_16x16x32_bf16(axl, bwh, acc, 0, 0, 0);
    }
#pragma unroll
    for (int r = 0; r < 4; ++r) {
        const int m = kb * 4 + r, c = wv * 16 + ml;
        unsigned hi = bf16_rne(acc[r]);
        float hif = __uint_as_float(hi << 16);
        hsh[m * 72 + c] = (unsigned short)hi;
        hsl[m * 72 + c] = (unsigned short)bf16_rne(acc[r] - hif);
    }
    __syncthreads();

    // e-MFMA: e[16][24] = h[16][64] @ Acat[24][64]^T (waves 0,1)
    if (wv < 2) {
        f32x4 e4 = {0.f, 0.f, 0.f, 0.f};
#pragma unroll
        for (int ks = 0; ks < 2; ++ks) {
            const int ko = ks * 32 + kb * 8;
            bf16x8 ah = *(const bf16x8*)&hsh[ml * 72 + ko];
            bf16x8 al = *(const bf16x8*)&hsl[ml * 72 + ko];
            bf16x8 bh = *(const bf16x8*)&Ach[(wv * 16 + ml) * 72 + ko];
            bf16x8 bl = *(const bf16x8*)&Acl[(wv * 16 + ml) * 72 + ko];
            e4 = __builtin_amdgcn_mfma_f32_16x16x32_bf16(ah, bh, e4, 0, 0, 0);
            e4 = __builtin_amdgcn_mfma_f32_16x16x32_bf16(ah, bl, e4, 0, 0, 0);
            e4 = __builtin_amdgcn_mfma_f32_16x16x32_bf16(al, bh, e4, 0, 0, 0);
        }
#pragma unroll
        for (int r = 0; r < 4; ++r) {
            const int m = kb * 4 + r, n = wv * 16 + ml;
            if (n < 12)
                esrc[(row0 + m) * 12 + n] = (e4[r] + ab[n]) * L2E;
            else if (n < 24)
                edstT[(b * 12 + (n - 12)) * 256 + ibase + m] = e4[r] * L2E;
        }
    }

    // hT write packed (uint = 2 bf16 along j)
#pragma unroll
    for (int it = 0; it < 2; ++it) {
        int e2 = t + 256 * it;               // 0..511
        int d = e2 >> 3, j2 = (e2 & 7) * 2;
        unsigned lo16 = hsh[j2 * 72 + d], hi16 = hsh[(j2 + 1) * 72 + d];
        *(unsigned*)&hTg[(b * 64 + d) * 256 + ibase + j2] = lo16 | (hi16 << 16);
    }
}

// ---- kernel 2: masked 12-head softmax (no-max, pre-scaled) + MFMA PV ----
// 1024 blocks x 256 thr (4 waves); wave = 1 row, lane owns j=4*lane..+3.
// 4 blocks/CU -> 4 waves/SIMD for latency hiding (grid was the occupancy cap).
__global__ __launch_bounds__(256) void k2_attn(
    const int* __restrict__ adj, const int* __restrict__ adjin, const int* __restrict__ adjout,
    const float* __restrict__ esrc, const float* __restrict__ edstT,
    const unsigned short* __restrict__ hTg,
    float* __restrict__ out)
{
    __shared__ unsigned short Ph[16 * 264];   // rows 0..3 = P bf16; rows 4..15 zeroed

    const int t = threadIdx.x;
    const int b  = blockIdx.x >> 6;
    const int i0 = (blockIdx.x & 63) * 4;
    const int lane = t & 63;
    const int wv = t >> 6;                    // 0..3 = row
    const int gi = b * 256 + i0 + wv;

    // zero Ph rows 4..15 (u16 idx 1056..4224 = 396 uint4)
    {
        uint4* z = (uint4*)&Ph[1056];
        const uint4 z4 = make_uint4(0, 0, 0, 0);
        if (t < 198) { z[t] = z4; z[t + 198] = z4; }
    }

    // masks: 4 j per lane, 1 int4 per type (coalesced)
    const int4 M0 = *(const int4*)(adj    + (size_t)gi * 256 + 4 * lane);
    const int4 M1 = *(const int4*)(adjin  + (size_t)gi * 256 + 4 * lane);
    const int4 M2 = *(const int4*)(adjout + (size_t)gi * 256 + 4 * lane);
    float fm[3][4];
    fm[0][0] = (float)M0.x; fm[0][1] = (float)M0.y; fm[0][2] = (float)M0.z; fm[0][3] = (float)M0.w;
    fm[1][0] = (float)M1.x; fm[1][1] = (float)M1.y; fm[1][2] = (float)M1.z; fm[1][3] = (float)M1.w;
    fm[2][0] = (float)M2.x; fm[2][1] = (float)M2.y; fm[2][2] = (float)M2.z; fm[2][3] = (float)M2.w;

    // e0 (pre-biased, pre-scaled by L2E in k1)
    const float4* ep = (const float4*)(esrc + (size_t)gi * 12);
    const float4 eA = ep[0], eB = ep[1], eC = ep[2];
    const float e0[12] = {eA.x, eA.y, eA.z, eA.w, eB.x, eB.y, eB.z, eB.w, eC.x, eC.y, eC.z, eC.w};

    float Pacc[4] = {0.f, 0.f, 0.f, 0.f};
#pragma unroll
    for (int hh = 0; hh < 12; ++hh) {
        const int grp = hh >> 2;
        const float4 ev = *(const float4*)(edstT + (size_t)(b * 12 + hh) * 256 + 4 * lane);
        const float evv[4] = {ev.x, ev.y, ev.z, ev.w};
        float p[4], s = 0.f;
#pragma unroll
        for (int k = 0; k < 4; ++k) {
            float v = e0[hh] + evv[k];
            v = fmaxf(v, 0.01f * v);                     // leaky in log2 domain
            p[k] = __builtin_amdgcn_exp2f(v) * fm[grp][k];
            s += p[k];
        }
#pragma unroll
        for (int off = 32; off >= 1; off >>= 1)
            s += __shfl_xor(s, off);                     // 64-lane reduce
        const float rinv = __builtin_amdgcn_rcpf(s);
#pragma unroll
        for (int k = 0; k < 4; ++k)
            Pacc[k] += p[k] * rinv;
    }
    {
        uint2 pk;
        pk.x = bf16_rne(Pacc[0]) | (bf16_rne(Pacc[1]) << 16);
        pk.y = bf16_rne(Pacc[2]) | (bf16_rne(Pacc[3]) << 16);
        *(uint2*)&Ph[wv * 264 + 4 * lane] = pk;
    }
    __syncthreads();

    // PV: out[4][64] = P[4][256] x hT^T ; B-frags from L2; wave -> 16-d slice
    const int ml = lane & 15, kb = lane >> 4;
    const unsigned short* hTb = hTg + ((size_t)b * 64 + wv * 16 + ml) * 256;
    f32x4 acc = {0.f, 0.f, 0.f, 0.f};
#pragma unroll
    for (int ks = 0; ks < 8; ++ks) {
        const int ko = ks * 32 + kb * 8;
        bf16x8 bh = *(const bf16x8*)&hTb[ko];
        bf16x8 ah = *(const bf16x8*)&Ph[ml * 264 + ko];
        acc = __builtin_amdgcn_mfma_f32_16x16x32_bf16(ah, bh, acc, 0, 0, 0);
    }
    if (kb == 0) {
#pragma unroll
        for (int r = 0; r < 4; ++r)
            out[(size_t)(b * 256 + i0 + r) * 64 + wv * 16 + ml] = acc[r] * (1.0f / 12.0f);
    }
}

extern "C" void kernel_launch(void* const* d_in, const int* in_sizes, int n_in,
                              void* d_out, int out_size, void* d_ws, size_t ws_size,
                              hipStream_t stream) {
    const float* x    = (const float*)d_in[0];
    const int*   adj  = (const int*)d_in[1];
    const int*   adji = (const int*)d_in[2];
    const int*   adjo = (const int*)d_in[3];
    const float* W    = (const float*)d_in[4];
    const float* A    = (const float*)d_in[5];
    const float* ab   = (const float*)d_in[6];
    float* out = (float*)d_out;

    unsigned short* hTg = (unsigned short*)d_ws;              // 512 KB
    float* esg  = (float*)((char*)d_ws + (512 << 10));        // 192 KB
    float* edTg = (float*)((char*)d_ws + (704 << 10));        // 192 KB

    k1_proj<<<256, 256, 0, stream>>>(x, W, A, ab, hTg, esg, edTg);
    k2_attn<<<1024, 256, 0, stream>>>(adj, adji, adjo, esg, edTg, hTg, out);
}

// Round 13
// 18.065 us; speedup vs baseline: 5.4151x; 1.0365x over previous
//
#include <hip/hip_runtime.h>

#define L2E 1.44269504088896340736f

typedef __attribute__((ext_vector_type(8))) short bf16x8;
typedef __attribute__((ext_vector_type(4))) float f32x4;

__device__ __forceinline__ unsigned bf16_rne(float v) {
    unsigned x = __float_as_uint(v);
    return (x + 0x7FFFu + ((x >> 16) & 1u)) >> 16;
}

__device__ __forceinline__ uint2 cvt_hi4(float4 v) {
    uint2 r;
    r.x = bf16_rne(v.x) | (bf16_rne(v.y) << 16);
    r.y = bf16_rne(v.z) | (bf16_rne(v.w) << 16);
    return r;
}

// ---- kernel 1 (hi-only, 8-row tiles): h=x@W^T ; esrc'=(h@A1^T+ab)*L2E ;
// edstT'=(h@A2^T)*L2E ; hT bf16 direct from accumulators.
// 512 blocks x 256 thr -> 2 blocks/CU (2 waves/SIMD).
__global__ __launch_bounds__(256) void k1_proj(
    const float* __restrict__ x, const float* __restrict__ W, const float* __restrict__ A,
    const float* __restrict__ ab,
    unsigned short* __restrict__ hTg, float* __restrict__ esrc, float* __restrict__ edstT)
{
    __shared__ unsigned short xh[8 * 136];    // x tile bf16 (hi only)
    __shared__ unsigned short wh[64 * 136];   // W bf16
    __shared__ unsigned short Ach[32 * 72];   // [A1;A2] bf16 (24 valid rows)
    __shared__ unsigned short hsh[16 * 72];   // h bf16 (rows 0..7 valid)

    const int t = threadIdx.x;
    const int row0 = blockIdx.x * 8;          // flat row over B*N
    const int b = row0 >> 8;
    const int ibase = row0 & 255;
    const int lane = t & 63, wv = t >> 6;     // 4 waves
    const int ml = lane & 15, kb = lane >> 4;

    // stage x (8x128 = 256 float4, 1/thread, coalesced)
    {
        int r = t >> 5, c = (t & 31) * 4;
        *(uint2*)&xh[r * 136 + c] = cvt_hi4(*(const float4*)&x[row0 * 128 + 4 * t]);
    }
    // stage W (64x128 = 2048 float4, 8/thread)
#pragma unroll
    for (int p = 0; p < 8; ++p) {
        int q = t + 256 * p;
        int r = q >> 5, c = (q & 31) * 4;
        *(uint2*)&wh[r * 136 + c] = cvt_hi4(*(const float4*)&W[4 * q]);
    }
    // stage Acat (24x64 pad 32)
#pragma unroll
    for (int p = 0; p < 2; ++p) {
        int q = t + 256 * p;
        int n = q >> 4, d = (q & 15) * 4;
        float4 v = make_float4(0.f, 0.f, 0.f, 0.f);
        if (n < 24) {
            int nn = (n < 12) ? n : n - 12;
            v = *(const float4*)&A[nn * 128 + ((n < 12) ? 0 : 64) + d];
        }
        *(uint2*)&Ach[n * 72 + d] = cvt_hi4(v);
    }
    __syncthreads();

    // h-MFMA: h[8(16)][64] = x @ W^T, K=128, hi-only (4 MFMA/wave; wv = N-tile)
    f32x4 acc = {0.f, 0.f, 0.f, 0.f};
#pragma unroll
    for (int ks = 0; ks < 4; ++ks) {
        const int ko = ks * 32 + kb * 8;
        bf16x8 ax = *(const bf16x8*)&xh[(ml & 7) * 136 + ko];   // rows 8-15 dup rows 0-7
        bf16x8 bw = *(const bf16x8*)&wh[(wv * 16 + ml) * 136 + ko];
        acc = __builtin_amdgcn_mfma_f32_16x16x32_bf16(ax, bw, acc, 0, 0, 0);
    }
    // rows m = kb*4+r < 8 are real; hT written straight from acc
    if (kb < 2) {
        const int d = wv * 16 + ml;
        uint2 pk;
        pk.x = bf16_rne(acc[0]) | (bf16_rne(acc[1]) << 16);
        pk.y = bf16_rne(acc[2]) | (bf16_rne(acc[3]) << 16);
        *(uint2*)&hTg[(size_t)(b * 64 + d) * 256 + ibase + kb * 4] = pk;
#pragma unroll
        for (int r = 0; r < 4; ++r)
            hsh[(kb * 4 + r) * 72 + d] = (unsigned short)bf16_rne(acc[r]);
    }
    __syncthreads();

    // e-MFMA (waves 0,1): e[8(16)][24(32)] = h @ Acat^T, K=64, hi-only (2 MFMA)
    if (wv < 2) {
        const int n_e = wv * 16 + ml;          // 0..31
        f32x4 e4 = {0.f, 0.f, 0.f, 0.f};
#pragma unroll
        for (int ks = 0; ks < 2; ++ks) {
            const int ko = ks * 32 + kb * 8;
            bf16x8 ah = *(const bf16x8*)&hsh[ml * 72 + ko];     // rows 8-15 garbage-safe
            bf16x8 bh = *(const bf16x8*)&Ach[n_e * 72 + ko];
            e4 = __builtin_amdgcn_mfma_f32_16x16x32_bf16(ah, bh, e4, 0, 0, 0);
        }
        if (kb < 2) {
            if (n_e < 12) {
                const float abv = ab[n_e];
#pragma unroll
                for (int r = 0; r < 4; ++r)
                    esrc[(size_t)(row0 + kb * 4 + r) * 12 + n_e] = (e4[r] + abv) * L2E;
            } else if (n_e < 24) {
                float4 ev;
                ev.x = e4[0] * L2E; ev.y = e4[1] * L2E;
                ev.z = e4[2] * L2E; ev.w = e4[3] * L2E;
                *(float4*)&edstT[(size_t)(b * 12 + (n_e - 12)) * 256 + ibase + kb * 4] = ev;
            }
        }
    }
}

// ---- kernel 2 (R5 exact): masked 12-head softmax (no-max, pre-scaled) + MFMA PV ----
// 512 blocks x 256 thr (4 waves); wave = 2 rows (32-lane groups); block = 8 rows.
__global__ __launch_bounds__(256) void k2_attn(
    const int* __restrict__ adj, const int* __restrict__ adjin, const int* __restrict__ adjout,
    const float* __restrict__ esrc, const float* __restrict__ edstT,
    const unsigned short* __restrict__ hTg,
    float* __restrict__ out)
{
    __shared__ unsigned short Ph[16 * 264];   // rows 0..7 = P bf16; rows 8..15 zeroed

    const int t = threadIdx.x;
    const int b  = blockIdx.x >> 5;
    const int i0 = (blockIdx.x & 31) * 8;
    const int lane = t & 63;
    const int wv = t >> 6;                    // 0..3
    const int g = lane >> 5;                  // half-wave -> row parity
    const int q = lane & 31;                  // j-block: j = 8q..8q+7
    const int row = wv * 2 + g;               // 0..7
    const int gi = b * 256 + i0 + row;

    // zero Ph rows 8..15
    {
        uint4* z = (uint4*)&Ph[8 * 264];
        if (t < 264) z[t] = make_uint4(0, 0, 0, 0);
    }

    // masks: 8 j per lane, 2 int4 per type
    const int4* mp0 = (const int4*)(adj    + (size_t)gi * 256 + 8 * q);
    const int4* mp1 = (const int4*)(adjin  + (size_t)gi * 256 + 8 * q);
    const int4* mp2 = (const int4*)(adjout + (size_t)gi * 256 + 8 * q);
    int4 Ma0 = mp0[0], Ma1 = mp0[1];
    int4 Mb0 = mp1[0], Mb1 = mp1[1];
    int4 Mc0 = mp2[0], Mc1 = mp2[1];
    float fm[3][8];
    fm[0][0] = (float)Ma0.x; fm[0][1] = (float)Ma0.y; fm[0][2] = (float)Ma0.z; fm[0][3] = (float)Ma0.w;
    fm[0][4] = (float)Ma1.x; fm[0][5] = (float)Ma1.y; fm[0][6] = (float)Ma1.z; fm[0][7] = (float)Ma1.w;
    fm[1][0] = (float)Mb0.x; fm[1][1] = (float)Mb0.y; fm[1][2] = (float)Mb0.z; fm[1][3] = (float)Mb0.w;
    fm[1][4] = (float)Mb1.x; fm[1][5] = (float)Mb1.y; fm[1][6] = (float)Mb1.z; fm[1][7] = (float)Mb1.w;
    fm[2][0] = (float)Mc0.x; fm[2][1] = (float)Mc0.y; fm[2][2] = (float)Mc0.z; fm[2][3] = (float)Mc0.w;
    fm[2][4] = (float)Mc1.x; fm[2][5] = (float)Mc1.y; fm[2][6] = (float)Mc1.z; fm[2][7] = (float)Mc1.w;

    // e0 (pre-biased, pre-scaled by L2E in k1)
    const float4* ep = (const float4*)(esrc + (size_t)gi * 12);
    const float4 eA = ep[0], eB = ep[1], eC = ep[2];
    const float e0[12] = {eA.x, eA.y, eA.z, eA.w, eB.x, eB.y, eB.z, eB.w, eC.x, eC.y, eC.z, eC.w};

    float Pacc[8] = {0.f, 0.f, 0.f, 0.f, 0.f, 0.f, 0.f, 0.f};
#pragma unroll
    for (int hh = 0; hh < 12; ++hh) {
        const int grp = hh >> 2;
        const float4* evp = (const float4*)(edstT + (size_t)(b * 12 + hh) * 256 + 8 * q);
        const float4 ev0 = evp[0], ev1 = evp[1];
        const float evv[8] = {ev0.x, ev0.y, ev0.z, ev0.w, ev1.x, ev1.y, ev1.z, ev1.w};
        float p[8], s = 0.f;
#pragma unroll
        for (int k = 0; k < 8; ++k) {
            float v = e0[hh] + evv[k];
            v = fmaxf(v, 0.01f * v);                     // leaky in log2 domain
            p[k] = __builtin_amdgcn_exp2f(v) * fm[grp][k];
            s += p[k];
        }
#pragma unroll
        for (int off = 16; off >= 1; off >>= 1)
            s += __shfl_xor(s, off);                     // 32-lane group reduce
        const float rinv = __builtin_amdgcn_rcpf(s);
#pragma unroll
        for (int k = 0; k < 8; ++k)
            Pacc[k] += p[k] * rinv;
    }
    {
        uint4 pk;
        pk.x = bf16_rne(Pacc[0]) | (bf16_rne(Pacc[1]) << 16);
        pk.y = bf16_rne(Pacc[2]) | (bf16_rne(Pacc[3]) << 16);
        pk.z = bf16_rne(Pacc[4]) | (bf16_rne(Pacc[5]) << 16);
        pk.w = bf16_rne(Pacc[6]) | (bf16_rne(Pacc[7]) << 16);
        *(uint4*)&Ph[row * 264 + 8 * q] = pk;
    }
    __syncthreads();

    // PV: out[8][64] = P[8][256] x hT^T ; B-frags from L2; wave -> 16-d slice
    const int ml = lane & 15, kb = lane >> 4;
    const unsigned short* hTb = hTg + ((size_t)b * 64 + wv * 16 + ml) * 256;
    f32x4 acc = {0.f, 0.f, 0.f, 0.f};
#pragma unroll
    for (int ks = 0; ks < 8; ++ks) {
        const int ko = ks * 32 + kb * 8;
        bf16x8 bh = *(const bf16x8*)&hTb[ko];
        bf16x8 ah = *(const bf16x8*)&Ph[ml * 264 + ko];
        acc = __builtin_amdgcn_mfma_f32_16x16x32_bf16(ah, bh, acc, 0, 0, 0);
    }
    if (kb < 2) {
#pragma unroll
        for (int r = 0; r < 4; ++r) {
            const int m = kb * 4 + r;     // 0..7
            out[(size_t)(b * 256 + i0 + m) * 64 + wv * 16 + ml] = acc[r] * (1.0f / 12.0f);
        }
    }
}

extern "C" void kernel_launch(void* const* d_in, const int* in_sizes, int n_in,
                              void* d_out, int out_size, void* d_ws, size_t ws_size,
                              hipStream_t stream) {
    const float* x    = (const float*)d_in[0];
    const int*   adj  = (const int*)d_in[1];
    const int*   adji = (const int*)d_in[2];
    const int*   adjo = (const int*)d_in[3];
    const float* W    = (const float*)d_in[4];
    const float* A    = (const float*)d_in[5];
    const float* ab   = (const float*)d_in[6];
    float* out = (float*)d_out;

    unsigned short* hTg = (unsigned short*)d_ws;              // 512 KB
    float* esg  = (float*)((char*)d_ws + (512 << 10));        // 192 KB
    float* edTg = (float*)((char*)d_ws + (704 << 10));        // 192 KB

    k1_proj<<<512, 256, 0, stream>>>(x, W, A, ab, hTg, esg, edTg);
    k2_attn<<<512, 256, 0, stream>>>(adj, adji, adjo, esg, edTg, hTg, out);
}